// Round 8
// baseline (1082.463 us; speedup 1.0000x reference)
//
#include <hip/hip_runtime.h>
#include <hip/hip_bf16.h>
#include <math.h>

#define B_   16
#define CIN  64
#define COUT 64
#define H_   128
#define W_   128
#define KK   25
#define HW   (H_ * W_)

// ---------------- Kernel 1: main conv (reflect pad) + cosine normalize -------
// Tile: 16x32 output pixels per block; 256 threads; each thread handles
// 2 pixels (r,c),(r+8,c) for all 64 output channels. Weight normalization
// recomputed per block into LDS (cheap: 1600x64 MACs) so ws holds only t.
#define TH 16
#define TW 32
#define PH (TH + 4)      // 20
#define PW (TW + 4)      // 36
#define PWP 37           // padded LDS stride

__global__ __launch_bounds__(256) void k_conv(const float* __restrict__ x,
                                              const float* __restrict__ wraw,
                                              __hip_bfloat16* __restrict__ t) {
    __shared__ float patch[PH * PWP];
    __shared__ __align__(16) float wl[KK * COUT];
    __shared__ float invn[COUT * KK];

    const int tid = threadIdx.x;
    const int b  = blockIdx.z;
    const int h0 = blockIdx.y * TH;
    const int w0 = blockIdx.x * TW;
    const int r = tid >> 5;       // 0..7
    const int c = tid & 31;       // 0..31

    // invn[o*25+kk] = 1/max(||w[o,:,kh,kw]||_2, 1e-12)
    for (int g = tid; g < COUT * KK; g += 256) {
        int o = g / KK, kk = g % KK;
        float s = 0.f;
        #pragma unroll 8
        for (int i = 0; i < CIN; ++i) {
            float v = wraw[(size_t)(o * CIN + i) * KK + kk];
            s += v * v;
        }
        invn[g] = 1.f / fmaxf(sqrtf(s), 1e-12f);
    }
    __syncthreads();

    float acc0[COUT], acc1[COUT];
    #pragma unroll
    for (int o = 0; o < COUT; ++o) { acc0[o] = 0.f; acc1[o] = 0.f; }
    float xsq0 = 0.f, xsq1 = 0.f;

    for (int i = 0; i < CIN; ++i) {
        // reflect-padded 20x36 patch for input channel i
        const float* xc = x + (size_t)(b * CIN + i) * HW;
        for (int idx = tid; idx < PH * PW; idx += 256) {
            int rr = idx / PW, cc = idx % PW;
            int hh = h0 - 2 + rr; hh = hh < 0 ? -hh : (hh > H_ - 1 ? 2 * (H_ - 1) - hh : hh);
            int ww = w0 - 2 + cc; ww = ww < 0 ? -ww : (ww > W_ - 1 ? 2 * (W_ - 1) - ww : ww);
            patch[rr * PWP + cc] = xc[hh * W_ + ww];
        }
        // normalized weights for channel i: wl[kk*64+o] = |w[o,i,kk]| * invn[o,kk]
        for (int idx = tid; idx < KK * COUT; idx += 256) {
            int kk = idx >> 6, o = idx & 63;
            wl[idx] = fabsf(wraw[(size_t)(o * CIN + i) * KK + kk]) * invn[o * KK + kk];
        }
        __syncthreads();

        for (int kh = 0; kh < 5; ++kh) {
            for (int kw = 0; kw < 5; ++kw) {
                float p0 = patch[(r + kh) * PWP + (c + kw)];
                float p1 = patch[(r + 8 + kh) * PWP + (c + kw)];
                xsq0 += p0 * p0;
                xsq1 += p1 * p1;
                const float4* wrow = (const float4*)(wl + (kh * 5 + kw) * COUT);
                #pragma unroll
                for (int oc = 0; oc < COUT / 4; ++oc) {
                    float4 wv = wrow[oc];
                    acc0[4 * oc + 0] += p0 * wv.x;
                    acc0[4 * oc + 1] += p0 * wv.y;
                    acc0[4 * oc + 2] += p0 * wv.z;
                    acc0[4 * oc + 3] += p0 * wv.w;
                    acc1[4 * oc + 0] += p1 * wv.x;
                    acc1[4 * oc + 1] += p1 * wv.y;
                    acc1[4 * oc + 2] += p1 * wv.z;
                    acc1[4 * oc + 3] += p1 * wv.w;
                }
            }
        }
        __syncthreads();
    }

    float inv0 = rsqrtf(xsq0 + 1e-8f);
    float inv1 = rsqrtf(xsq1 + 1e-8f);
    int h1 = h0 + r, h2 = h0 + r + 8, wc = w0 + c;
    #pragma unroll
    for (int o = 0; o < COUT; ++o) {
        t[((size_t)(b * COUT + o) * H_ + h1) * W_ + wc] = __float2bfloat16(acc0[o] * inv0);
        t[((size_t)(b * COUT + o) * H_ + h2) * W_ + wc] = __float2bfloat16(acc1[o] * inv1);
    }
}

// ---------------- Kernel 2: depthwise 5x5 DoG, zero pad, FP32 OUTPUT ---------
#define SH 16
__global__ __launch_bounds__(256) void k_dog(const __hip_bfloat16* __restrict__ t,
                                             float* __restrict__ out) {
    __shared__ float tile[(SH + 4) * (W_ + 4)];   // 20 x 132
    const int bo = blockIdx.y;                    // b*COUT + o
    const int h0 = blockIdx.x * SH;
    const int tid = threadIdx.x;

    float sm[25];
    {
        const float se2 = 2.f * 1.2f * 1.2f;
        const float si2 = 2.f * 1.4f * 1.4f;
        const float twopi = 6.28318530717958647692f;
        const float ae = 1.f / (twopi * 1.2f * 1.2f);
        const float ai = 1.f / (twopi * 1.4f * 1.4f);
        const float c0 = ae - ai;
        #pragma unroll
        for (int kk = 0; kk < 25; ++kk) {
            int dx = kk / 5 - 2, dy = kk % 5 - 2;
            float r2 = (float)(dx * dx + dy * dy);
            sm[kk] = (ae * expf(-r2 / se2) - ai * expf(-r2 / si2)) / c0;
        }
    }

    const __hip_bfloat16* tc = t + (size_t)bo * HW;
    for (int idx = tid; idx < (SH + 4) * (W_ + 4); idx += 256) {
        int rr = idx / (W_ + 4), cc = idx % (W_ + 4);
        int hh = h0 - 2 + rr, ww = cc - 2;
        float v = 0.f;
        if (hh >= 0 && hh < H_ && ww >= 0 && ww < W_) v = __bfloat162float(tc[hh * W_ + ww]);
        tile[idx] = v;
    }
    __syncthreads();

    #pragma unroll
    for (int j = 0; j < 8; ++j) {
        int p = tid + j * 256;
        int rr = p >> 7, cc = p & 127;
        float s = 0.f;
        #pragma unroll
        for (int kh = 0; kh < 5; ++kh) {
            #pragma unroll
            for (int kw = 0; kw < 5; ++kw) {
                s += sm[kh * 5 + kw] * tile[(rr + kh) * (W_ + 4) + cc + kw];
            }
        }
        out[(size_t)bo * HW + (h0 + rr) * W_ + cc] = s;   // FP32 store
    }
}

// -----------------------------------------------------------------------------
extern "C" void kernel_launch(void* const* d_in, const int* in_sizes, int n_in,
                              void* d_out, int out_size, void* d_ws, size_t ws_size,
                              hipStream_t stream) {
    const float* x = (const float*)d_in[0];
    const float* w = (const float*)d_in[1];
    // H-fp32out: reference's output dtype is fp32 (y computed from fp32 x),
    // so d_out is float*. Rounds 2-7 wrote bf16 here -> harness fp32-read saw
    // a shifted/downsampled copy -> the frozen absmax 2.15625.
    float* out = (float*)d_out;

    __hip_bfloat16* t = (__hip_bfloat16*)d_ws;    // 32 MiB intermediate (pre-DoG y1)

    dim3 g2(W_ / TW, H_ / TH, B_);   // 4 x 8 x 16 = 512 blocks
    k_conv<<<g2, 256, 0, stream>>>(x, w, t);

    dim3 g3(H_ / SH, B_ * COUT);     // 8 x 1024 blocks
    k_dog<<<g3, 256, 0, stream>>>(t, out);
}

// Round 9
// 261.504 us; speedup vs baseline: 4.1394x; 4.1394x over previous
//
#include <hip/hip_runtime.h>
#include <hip/hip_bf16.h>
#include <math.h>

#define B_   16
#define CIN  64
#define COUT 64
#define H_   128
#define W_   128
#define KK   25
#define HW   (H_ * W_)

typedef short  bf16x8 __attribute__((ext_vector_type(8)));
typedef short  s16x4  __attribute__((ext_vector_type(4)));
typedef float  f32x16 __attribute__((ext_vector_type(16)));

__device__ __forceinline__ short f2bs(float v) {
    __hip_bfloat16 h = __float2bfloat16(v);
    return *reinterpret_cast<short*>(&h);
}
__device__ __forceinline__ float bs2f(short s) {
    unsigned int u = ((unsigned int)(unsigned short)s) << 16;
    return __uint_as_float(u);
}

// ---------------- Kernel 0: precompute normalized bf16 weights ---------------
// wnb[kk][oc][cin] = bf16( |w[oc,cin,kk]| / max(||w[oc,:,kk]||_2, 1e-12) )
__global__ __launch_bounds__(256) void k_wprep(const float* __restrict__ w,
                                               short* __restrict__ wnb) {
    int g = blockIdx.x * 256 + threadIdx.x;   // (oc, kk)
    if (g >= COUT * KK) return;
    int o = g / KK, kk = g % KK;
    float s = 0.f;
    #pragma unroll 8
    for (int i = 0; i < CIN; ++i) {
        float v = w[(size_t)(o * CIN + i) * KK + kk];
        s += v * v;
    }
    float inv = 1.f / fmaxf(sqrtf(s), 1e-12f);
    for (int i = 0; i < CIN; ++i) {
        float v = fabsf(w[(size_t)(o * CIN + i) * KK + kk]) * inv;
        wnb[(size_t)(kk * COUT + o) * CIN + i] = f2bs(v);
    }
}

// ---------------- Kernel 1: MFMA implicit-GEMM conv + cosine normalize -------
// Block: 256 thr = 4 waves. Output tile: 4 h-rows x 32 w-cols x 64 oc.
// Wave wv owns h-row wv (m = w-col 0..31), 2 n-tiles (oc 0..31 / 32..63).
// K = 25 taps x 64 cin, mfma_f32_32x32x16_bf16 (4 k-steps per tap).
#define XPAD 72          // cin stride in LDS (36 dwords -> conflict-free frags)
#define NS   288         // 8 x 36 spatial window
#define TPAD 136         // transpose row stride (16B-aligned runs)

__global__ __launch_bounds__(256) void k_conv(const float* __restrict__ x,
                                              const short* __restrict__ wnb,
                                              __hip_bfloat16* __restrict__ t) {
    __shared__ short xin[NS * XPAD];      // 41472 B; reused as trans[64][TPAD]
    __shared__ short wtap[COUT * XPAD];   // 9216 B
    __shared__ float s2win[NS];
    __shared__ float xsq[128];

    const int tid  = threadIdx.x;
    const int lane = tid & 63;
    const int wv   = tid >> 6;            // wave id = h-row
    const int n    = lane & 31;           // n index (oc within tile) / m (w-col)
    const int q    = lane >> 5;           // k-half selector
    const int b    = blockIdx.z;
    const int h0   = blockIdx.y * 4;
    const int w0   = blockIdx.x * 32;

    // ---- stage reflect-padded window: 8 rows x 36 cols x 64 cin -> bf16 LDS
    const float* xb = x + (size_t)b * CIN * HW;
    for (int idx = tid; idx < NS * CIN; idx += 256) {
        int s  = idx % NS;                // spatial fast -> coalesced-ish global
        int ci = idx / NS;
        int r = s / 36, c = s % 36;
        int hh = h0 - 2 + r; hh = hh < 0 ? -hh : (hh > H_ - 1 ? 2 * (H_ - 1) - hh : hh);
        int ww = w0 - 2 + c; ww = ww < 0 ? -ww : (ww > W_ - 1 ? 2 * (W_ - 1) - ww : ww);
        xin[s * XPAD + ci] = f2bs(xb[(size_t)ci * HW + hh * W_ + ww]);
    }
    __syncthreads();

    // ---- per-spatial sum of squares over cin
    for (int s = tid; s < NS; s += 256) {
        float a = 0.f;
        #pragma unroll 8
        for (int ci = 0; ci < CIN; ++ci) {
            float v = bs2f(xin[s * XPAD + ci]);
            a += v * v;
        }
        s2win[s] = a;
    }
    __syncthreads();

    // ---- xsq per output pixel = 5x5 window sum of s2win
    if (tid < 128) {
        int hr = tid >> 5, cl = tid & 31;
        float a = 0.f;
        #pragma unroll
        for (int kh = 0; kh < 5; ++kh)
            #pragma unroll
            for (int kw = 0; kw < 5; ++kw)
                a += s2win[(hr + kh) * 36 + cl + kw];
        xsq[tid] = a;
    }

    f32x16 acc0, acc1;
    #pragma unroll
    for (int i = 0; i < 16; ++i) { acc0[i] = 0.f; acc1[i] = 0.f; }

    // ---- K loop: 25 taps x 64 cin
    for (int kk = 0; kk < KK; ++kk) {
        __syncthreads();                  // prev-iter wtap reads done (also covers xsq)
        const short* wsrc = wnb + (size_t)kk * COUT * CIN;
        for (int idx = tid; idx < COUT * CIN / 8; idx += 256) {   // 512 x 16B chunks
            int oc = idx >> 3, c8 = (idx & 7) * 8;
            *(bf16x8*)&wtap[oc * XPAD + c8] = *(const bf16x8*)&wsrc[oc * CIN + c8];
        }
        __syncthreads();

        const int kh = kk / 5, kw = kk % 5;
        const int sp = (wv + kh) * 36 + n + kw;   // A-row spatial index for lane
        #pragma unroll
        for (int ks = 0; ks < 4; ++ks) {
            bf16x8 a  = *(const bf16x8*)&xin[sp * XPAD + ks * 16 + q * 8];
            bf16x8 b0 = *(const bf16x8*)&wtap[n * XPAD + ks * 16 + q * 8];
            bf16x8 b1 = *(const bf16x8*)&wtap[(32 + n) * XPAD + ks * 16 + q * 8];
            acc0 = __builtin_amdgcn_mfma_f32_32x32x16_bf16(a, b0, acc0, 0, 0, 0);
            acc1 = __builtin_amdgcn_mfma_f32_32x32x16_bf16(a, b1, acc1, 0, 0, 0);
        }
    }
    __syncthreads();                      // xin dead; reuse as trans

    // ---- epilogue: y = acc * rsqrt(xsq), transpose via LDS, coalesced store
    short* trans = xin;                   // trans[oc][TPAD]
    #pragma unroll
    for (int g4 = 0; g4 < 4; ++g4) {      // reg groups of 4 -> 4 consecutive pixels
        int px0 = wv * 32 + 8 * g4 + 4 * q;
        s16x4 v0, v1;
        #pragma unroll
        for (int j = 0; j < 4; ++j) {
            float inv = rsqrtf(xsq[px0 + j] + 1e-8f);
            v0[j] = f2bs(acc0[4 * g4 + j] * inv);
            v1[j] = f2bs(acc1[4 * g4 + j] * inv);
        }
        *(s16x4*)&trans[n * TPAD + px0]        = v0;
        *(s16x4*)&trans[(32 + n) * TPAD + px0] = v1;
    }
    __syncthreads();

    {   // 256 runs: (oc, hr) -> 32 bf16 = 64 B contiguous global
        int oc = tid >> 2, hr = tid & 3;
        const short* src = &trans[oc * TPAD + hr * 32];
        __hip_bfloat16* dst = t + ((size_t)(b * COUT + oc) * H_ + h0 + hr) * W_ + w0;
        float4 a0 = *(const float4*)(src);
        float4 a1 = *(const float4*)(src + 8);
        float4 a2 = *(const float4*)(src + 16);
        float4 a3 = *(const float4*)(src + 24);
        *(float4*)(dst)      = a0;
        *(float4*)(dst + 8)  = a1;
        *(float4*)(dst + 16) = a2;
        *(float4*)(dst + 24) = a3;
    }
}

// ---------------- Kernel 2: depthwise 5x5 DoG, zero pad, fp32 out ------------
#define SH 16
__global__ __launch_bounds__(256) void k_dog(const __hip_bfloat16* __restrict__ t,
                                             float* __restrict__ out) {
    __shared__ float tile[(SH + 4) * (W_ + 4)];
    const int bo = blockIdx.y;
    const int h0 = blockIdx.x * SH;
    const int tid = threadIdx.x;

    float sm[25];
    {
        const float se2 = 2.f * 1.2f * 1.2f;
        const float si2 = 2.f * 1.4f * 1.4f;
        const float twopi = 6.28318530717958647692f;
        const float ae = 1.f / (twopi * 1.2f * 1.2f);
        const float ai = 1.f / (twopi * 1.4f * 1.4f);
        const float c0 = ae - ai;
        #pragma unroll
        for (int kk = 0; kk < 25; ++kk) {
            int dx = kk / 5 - 2, dy = kk % 5 - 2;
            float r2 = (float)(dx * dx + dy * dy);
            sm[kk] = (ae * expf(-r2 / se2) - ai * expf(-r2 / si2)) / c0;
        }
    }

    const __hip_bfloat16* tc = t + (size_t)bo * HW;
    for (int idx = tid; idx < (SH + 4) * (W_ + 4); idx += 256) {
        int rr = idx / (W_ + 4), cc = idx % (W_ + 4);
        int hh = h0 - 2 + rr, ww = cc - 2;
        float v = 0.f;
        if (hh >= 0 && hh < H_ && ww >= 0 && ww < W_) v = __bfloat162float(tc[hh * W_ + ww]);
        tile[idx] = v;
    }
    __syncthreads();

    #pragma unroll
    for (int j = 0; j < 8; ++j) {
        int p = tid + j * 256;
        int rr = p >> 7, cc = p & 127;
        float s = 0.f;
        #pragma unroll
        for (int kh = 0; kh < 5; ++kh)
            #pragma unroll
            for (int kw = 0; kw < 5; ++kw)
                s += sm[kh * 5 + kw] * tile[(rr + kh) * (W_ + 4) + cc + kw];
        out[(size_t)bo * HW + (h0 + rr) * W_ + cc] = s;
    }
}

// -----------------------------------------------------------------------------
extern "C" void kernel_launch(void* const* d_in, const int* in_sizes, int n_in,
                              void* d_out, int out_size, void* d_ws, size_t ws_size,
                              hipStream_t stream) {
    const float* x = (const float*)d_in[0];
    const float* w = (const float*)d_in[1];
    float* out = (float*)d_out;

    __hip_bfloat16* t = (__hip_bfloat16*)d_ws;    // 32 MiB intermediate

    // Normalized bf16 weights live in the TAIL of d_out (64 MiB fp32 buffer):
    // written by k_wprep, read by k_conv, fully overwritten by k_dog.
    // Keeps workspace usage at exactly 32 MiB. 204800 B, 16B-aligned offset.
    short* wnb = (short*)((char*)d_out + (size_t)67108864 - 204800);

    k_wprep<<<(COUT * KK + 255) / 256, 256, 0, stream>>>(w, wnb);

    dim3 g2(W_ / 32, H_ / 4, B_);    // 4 x 32 x 16 = 2048 blocks
    k_conv<<<g2, 256, 0, stream>>>(x, wnb, t);

    dim3 g3(H_ / SH, B_ * COUT);     // 8 x 1024 blocks
    k_dog<<<g3, 256, 0, stream>>>(t, out);
}

// Round 10
// 240.176 us; speedup vs baseline: 4.5070x; 1.0888x over previous
//
#include <hip/hip_runtime.h>
#include <hip/hip_bf16.h>
#include <math.h>

#define B_   16
#define CIN  64
#define COUT 64
#define H_   128
#define W_   128
#define KK   25
#define HW   (H_ * W_)

typedef short  bf16x8 __attribute__((ext_vector_type(8)));
typedef short  s16x4  __attribute__((ext_vector_type(4)));
typedef float  f32x16 __attribute__((ext_vector_type(16)));
typedef float  f32x4  __attribute__((ext_vector_type(4)));

__device__ __forceinline__ short f2bs(float v) {
    __hip_bfloat16 h = __float2bfloat16(v);
    return *reinterpret_cast<short*>(&h);
}
__device__ __forceinline__ float bs2f(short s) {
    unsigned int u = ((unsigned int)(unsigned short)s) << 16;
    return __uint_as_float(u);
}

// ---------------- Kernel 0: precompute normalized bf16 weights ---------------
// wnb[kk][oc][cin] = bf16( |w[oc,cin,kk]| / max(||w[oc,:,kk]||_2, 1e-12) )
__global__ __launch_bounds__(256) void k_wprep(const float* __restrict__ w,
                                               short* __restrict__ wnb) {
    int g = blockIdx.x * 256 + threadIdx.x;   // (oc, kk)
    if (g >= COUT * KK) return;
    int o = g / KK, kk = g % KK;
    float s = 0.f;
    #pragma unroll 8
    for (int i = 0; i < CIN; ++i) {
        float v = w[(size_t)(o * CIN + i) * KK + kk];
        s += v * v;
    }
    float inv = 1.f / fmaxf(sqrtf(s), 1e-12f);
    for (int i = 0; i < CIN; ++i) {
        float v = fabsf(w[(size_t)(o * CIN + i) * KK + kk]) * inv;
        wnb[(size_t)(kk * COUT + o) * CIN + i] = f2bs(v);
    }
}

// ---------------- Kernel 1: MFMA implicit-GEMM conv + cosine normalize -------
// Block: 256 thr = 4 waves. Output tile: 8 h x 32 w x 64 oc.
// Wave wv owns h-rows {2wv, 2wv+1} x 2 oc-tiles -> 4 MFMA per k-step from
// 2 A-reads + 2 B-reads (LDS:MFMA cycle ratio 48:32, was 36:16 in R9).
#define XP 72            // xin cin-stride in shorts (36 dwords -> 4n bank walk)
#define NR 12            // window rows  (8 + 4 halo)
#define NC 36            // window cols  (32 + 4 halo)
#define NS (NR * NC)     // 432
#define TP 264           // trans row stride in shorts

__global__ __launch_bounds__(256) void k_conv(const float* __restrict__ x,
                                              const short* __restrict__ wnb,
                                              __hip_bfloat16* __restrict__ t) {
    __shared__ short xin[NS * XP];        // 62208 B; reused as trans[64][TP]
    __shared__ short wtap[COUT * XP];     // 9216 B
    __shared__ float s2win[NS];           // 1728 B
    __shared__ float xsq[256];            // 1024 B   (total ~74 KB -> 2 blk/CU)

    const int tid  = threadIdx.x;
    const int lane = tid & 63;
    const int wv   = tid >> 6;
    const int n    = lane & 31;
    const int q    = lane >> 5;
    const int b    = blockIdx.z;
    const int h0   = blockIdx.y * 8;
    const int w0   = blockIdx.x * 32;

    // ---- stage reflect-padded window 12 x 36 x 64cin as bf16
    const float* xb = x + (size_t)b * CIN * HW;
    for (int idx = tid; idx < NS * CIN; idx += 256) {
        int s  = idx % NS;                 // spatial fast -> coalesced global
        int ci = idx / NS;
        int r = s / NC, c = s % NC;
        int hh = h0 - 2 + r; hh = hh < 0 ? -hh : (hh > H_ - 1 ? 2 * (H_ - 1) - hh : hh);
        int ww = w0 - 2 + c; ww = ww < 0 ? -ww : (ww > W_ - 1 ? 2 * (W_ - 1) - ww : ww);
        xin[s * XP + ci] = f2bs(xb[(size_t)ci * HW + hh * W_ + ww]);
    }
    __syncthreads();

    // ---- per-spatial sum of squares over cin (vectorized b128 reads)
    for (int s = tid; s < NS; s += 256) {
        const bf16x8* p = (const bf16x8*)&xin[s * XP];
        float a = 0.f;
        #pragma unroll
        for (int c8 = 0; c8 < 8; ++c8) {
            bf16x8 v = p[c8];
            #pragma unroll
            for (int j = 0; j < 8; ++j) { float f = bs2f(v[j]); a += f * f; }
        }
        s2win[s] = a;
    }
    __syncthreads();

    // ---- xsq per output pixel (8 x 32): 5x5 window sum of s2win
    {
        int hr = tid >> 5, cl = tid & 31;
        float a = 0.f;
        #pragma unroll
        for (int kh = 0; kh < 5; ++kh)
            #pragma unroll
            for (int kw = 0; kw < 5; ++kw)
                a += s2win[(hr + kh) * NC + cl + kw];
        xsq[tid] = a;
    }

    f32x16 acc00, acc01, acc10, acc11;
    #pragma unroll
    for (int i = 0; i < 16; ++i) { acc00[i] = 0.f; acc01[i] = 0.f; acc10[i] = 0.f; acc11[i] = 0.f; }

    // ---- K loop: 25 taps x 64 cin
    for (int kk = 0; kk < KK; ++kk) {
        __syncthreads();                   // prev-tap wtap reads done (also fences xsq/s2win)
        const short* wsrc = wnb + (size_t)kk * COUT * CIN;
        for (int idx = tid; idx < COUT * CIN / 8; idx += 256) {
            int oc = idx >> 3, c8 = (idx & 7) * 8;
            *(bf16x8*)&wtap[oc * XP + c8] = *(const bf16x8*)&wsrc[oc * CIN + c8];
        }
        __syncthreads();

        const int kh = kk / 5, kw = kk % 5;
        const int sp0 = (2 * wv + kh) * NC + n + kw;
        #pragma unroll
        for (int ks = 0; ks < 4; ++ks) {
            const int ko = ks * 16 + q * 8;
            bf16x8 a0 = *(const bf16x8*)&xin[sp0 * XP + ko];
            bf16x8 a1 = *(const bf16x8*)&xin[(sp0 + NC) * XP + ko];
            bf16x8 b0 = *(const bf16x8*)&wtap[n * XP + ko];
            bf16x8 b1 = *(const bf16x8*)&wtap[(32 + n) * XP + ko];
            acc00 = __builtin_amdgcn_mfma_f32_32x32x16_bf16(a0, b0, acc00, 0, 0, 0);
            acc01 = __builtin_amdgcn_mfma_f32_32x32x16_bf16(a0, b1, acc01, 0, 0, 0);
            acc10 = __builtin_amdgcn_mfma_f32_32x32x16_bf16(a1, b0, acc10, 0, 0, 0);
            acc11 = __builtin_amdgcn_mfma_f32_32x32x16_bf16(a1, b1, acc11, 0, 0, 0);
        }
    }
    __syncthreads();                       // xin dead; reuse as trans

    // ---- epilogue: y = acc * rsqrt(xsq); transpose via LDS; coalesced store
    short* trans = xin;
    const int hrA = 2 * wv, hrB = 2 * wv + 1;
    #pragma unroll
    for (int g4 = 0; g4 < 4; ++g4) {
        int wc0 = 8 * g4 + 4 * q;          // row-formula: (reg&3)+8*(reg>>2)+4*q
        s16x4 v00, v01, v10, v11;
        #pragma unroll
        for (int j = 0; j < 4; ++j) {
            float ia = rsqrtf(xsq[hrA * 32 + wc0 + j] + 1e-8f);
            float ib = rsqrtf(xsq[hrB * 32 + wc0 + j] + 1e-8f);
            v00[j] = f2bs(acc00[4 * g4 + j] * ia);
            v01[j] = f2bs(acc01[4 * g4 + j] * ia);
            v10[j] = f2bs(acc10[4 * g4 + j] * ib);
            v11[j] = f2bs(acc11[4 * g4 + j] * ib);
        }
        *(s16x4*)&trans[n * TP        + hrA * 32 + wc0] = v00;
        *(s16x4*)&trans[(32 + n) * TP + hrA * 32 + wc0] = v01;
        *(s16x4*)&trans[n * TP        + hrB * 32 + wc0] = v10;
        *(s16x4*)&trans[(32 + n) * TP + hrB * 32 + wc0] = v11;
    }
    __syncthreads();

    #pragma unroll
    for (int u = tid; u < 512; u += 256) { // (oc, hr): 32 bf16 = 64 B runs
        int oc = u >> 3, hr = u & 7;
        const short* src = &trans[oc * TP + hr * 32];
        __hip_bfloat16* dst = t + ((size_t)(b * COUT + oc) * H_ + h0 + hr) * W_ + w0;
        float4 a0 = *(const float4*)(src);
        float4 a1 = *(const float4*)(src + 8);
        float4 a2 = *(const float4*)(src + 16);
        float4 a3 = *(const float4*)(src + 24);
        *(float4*)(dst)      = a0;
        *(float4*)(dst + 8)  = a1;
        *(float4*)(dst + 16) = a2;
        *(float4*)(dst + 24) = a3;
    }
}

// ---------------- Kernel 2: depthwise 5x5 DoG, zero pad, fp32 out ------------
// Tile 32 rows x 128 cols; each thread: 4 rows x 4 consecutive cols.
// Per tap-row: 2 x ds_read_b128 feeds 4 outputs -> 10 b128 + 100 FMA per quad.
__global__ __launch_bounds__(256) void k_dog(const __hip_bfloat16* __restrict__ t,
                                             float* __restrict__ out) {
    __shared__ float tile[36 * 136];       // 19584 B
    const int bo  = blockIdx.y;
    const int h0  = blockIdx.x * 32;
    const int tid = threadIdx.x;

    float sm[25];
    {
        const float se2 = 2.f * 1.2f * 1.2f;
        const float si2 = 2.f * 1.4f * 1.4f;
        const float twopi = 6.28318530717958647692f;
        const float ae = 1.f / (twopi * 1.2f * 1.2f);
        const float ai = 1.f / (twopi * 1.4f * 1.4f);
        const float c0 = ae - ai;
        #pragma unroll
        for (int kk = 0; kk < 25; ++kk) {
            int dx = kk / 5 - 2, dy = kk % 5 - 2;
            float r2 = (float)(dx * dx + dy * dy);
            sm[kk] = (ae * expf(-r2 / se2) - ai * expf(-r2 / si2)) / c0;
        }
    }

    const __hip_bfloat16* tc = t + (size_t)bo * HW;
    for (int idx = tid; idx < 36 * 132; idx += 256) {
        int rr = idx / 132, cc = idx % 132;
        int hh = h0 - 2 + rr, ww = cc - 2;
        float v = 0.f;
        if (hh >= 0 && hh < H_ && ww >= 0 && ww < W_) v = __bfloat162float(tc[hh * W_ + ww]);
        tile[rr * 136 + cc] = v;
    }
    __syncthreads();

    const int cq = tid & 31;               // col quad: cols cq*4 .. cq*4+3
    const int r0 = tid >> 5;               // row group: rows r0 + 8*rr
    #pragma unroll
    for (int rr = 0; rr < 4; ++rr) {
        int r = r0 + 8 * rr;
        float s0 = 0.f, s1 = 0.f, s2 = 0.f, s3 = 0.f;
        #pragma unroll
        for (int kh = 0; kh < 5; ++kh) {
            const float* row = &tile[(r + kh) * 136 + cq * 4];
            f32x4 v0 = *(const f32x4*)(row);
            f32x4 v1 = *(const f32x4*)(row + 4);
            float vv[8] = { v0[0], v0[1], v0[2], v0[3], v1[0], v1[1], v1[2], v1[3] };
            #pragma unroll
            for (int kw = 0; kw < 5; ++kw) {
                float cf = sm[kh * 5 + kw];
                s0 += cf * vv[kw];
                s1 += cf * vv[kw + 1];
                s2 += cf * vv[kw + 2];
                s3 += cf * vv[kw + 3];
            }
        }
        float4 o4 = make_float4(s0, s1, s2, s3);
        *(float4*)&out[((size_t)bo * H_ + h0 + r) * W_ + cq * 4] = o4;
    }
}

// -----------------------------------------------------------------------------
extern "C" void kernel_launch(void* const* d_in, const int* in_sizes, int n_in,
                              void* d_out, int out_size, void* d_ws, size_t ws_size,
                              hipStream_t stream) {
    const float* x = (const float*)d_in[0];
    const float* w = (const float*)d_in[1];

    __hip_bfloat16* t = (__hip_bfloat16*)d_ws;    // 32 MiB intermediate

    // Normalized bf16 weights in the TAIL of d_out (64 MiB fp32 buffer):
    // written by k_wprep, read by k_conv, fully overwritten by k_dog.
    short* wnb = (short*)((char*)d_out + (size_t)67108864 - 204800);

    k_wprep<<<(COUT * KK + 255) / 256, 256, 0, stream>>>(w, wnb);

    dim3 g2(W_ / 32, H_ / 8, B_);    // 4 x 16 x 16 = 1024 blocks
    k_conv<<<g2, 256, 0, stream>>>(x, wnb, t);

    dim3 g3(H_ / 32, B_ * COUT);     // 4 x 1024 blocks
    k_dog<<<g3, 256, 0, stream>>>(t, (float*)d_out);
}

// Round 11
// 239.573 us; speedup vs baseline: 4.5183x; 1.0025x over previous
//
#include <hip/hip_runtime.h>
#include <hip/hip_bf16.h>
#include <math.h>

#define B_   16
#define CIN  64
#define COUT 64
#define H_   128
#define W_   128
#define KK   25
#define HW   (H_ * W_)

typedef short  bf16x8 __attribute__((ext_vector_type(8)));
typedef short  s16x4  __attribute__((ext_vector_type(4)));
typedef float  f32x16 __attribute__((ext_vector_type(16)));
typedef float  f32x4  __attribute__((ext_vector_type(4)));

__device__ __forceinline__ short f2bs(float v) {
    __hip_bfloat16 h = __float2bfloat16(v);
    return *reinterpret_cast<short*>(&h);
}
__device__ __forceinline__ float bs2f(short s) {
    unsigned int u = ((unsigned int)(unsigned short)s) << 16;
    return __uint_as_float(u);
}

// ---------------- Kernel 0: normalized bf16 weights in FRAGMENT ORDER --------
// wnb2[kk][ks][tile][lane][j] = wn[oc = tile*32 + (lane&31)]
//                                 [cin = ks*16 + (lane>>5)*8 + j]   at tap kk
// so k_conv's B-fragment load is ONE coalesced 1KB global_load_dwordx4/wave.
__global__ __launch_bounds__(256) void k_wprep(const float* __restrict__ w,
                                               short* __restrict__ wnb2) {
    __shared__ float wl[COUT * CIN];     // [o][i] for this tap
    __shared__ float inv[COUT];
    const int kk  = blockIdx.x;
    const int tid = threadIdx.x;

    for (int idx = tid; idx < COUT * CIN; idx += 256)
        wl[idx] = w[(size_t)idx * KK + kk];          // idx = o*64 + i
    __syncthreads();
    if (tid < COUT) {
        float s = 0.f;
        #pragma unroll 8
        for (int i = 0; i < CIN; ++i) { float v = wl[tid * CIN + i]; s += v * v; }
        inv[tid] = 1.f / fmaxf(sqrtf(s), 1e-12f);
    }
    __syncthreads();
    for (int idx = tid; idx < COUT * CIN; idx += 256) {
        int o = idx >> 6, c = idx & 63;
        int ks = c >> 4, q = (c >> 3) & 1, j = c & 7;
        int t = o >> 5, n = o & 31;
        int l = q * 32 + n;
        wnb2[((size_t)((kk * 4 + ks) * 2 + t) * 64 + l) * 8 + j] =
            f2bs(fabsf(wl[idx]) * inv[o]);
    }
}

// ---------------- Kernel 1: MFMA implicit-GEMM conv + cosine normalize -------
// Block: 256 thr = 4 waves; tile 8h x 32w x 64oc. Wave: 2 h-rows x 2 oc-tiles.
// BARRIER-FREE K-loop: A-frags from LDS xin, B-frags direct from global
// (coalesced, L2-resident 200KB shared by all blocks). 4 barriers/block total.
#define XP 72            // xin cin-stride in shorts
#define NR 12            // window rows (8 + 4 halo)
#define NC 36            // window cols (32 + 4 halo)
#define NS (NR * NC)     // 432
#define TP 264           // trans row stride in shorts

__global__ __launch_bounds__(256) void k_conv(const float* __restrict__ x,
                                              const short* __restrict__ wnb2,
                                              __hip_bfloat16* __restrict__ t) {
    __shared__ short xin[NS * XP];        // 62208 B; reused as trans[64][TP]
    __shared__ float s2win[NS];           // 1728 B
    __shared__ float xsq[256];            // 1024 B   (~65 KB -> 2 blk/CU)

    const int tid  = threadIdx.x;
    const int lane = tid & 63;
    const int wv   = tid >> 6;
    const int n    = lane & 31;
    const int q    = lane >> 5;
    const int b    = blockIdx.z;
    const int h0   = blockIdx.y * 8;
    const int w0   = blockIdx.x * 32;

    // ---- stage reflect-padded window 12 x 36 x 64cin as bf16
    const float* xb = x + (size_t)b * CIN * HW;
    for (int idx = tid; idx < NS * CIN; idx += 256) {
        int s  = idx % NS;
        int ci = idx / NS;
        int r = s / NC, c = s % NC;
        int hh = h0 - 2 + r; hh = hh < 0 ? -hh : (hh > H_ - 1 ? 2 * (H_ - 1) - hh : hh);
        int ww = w0 - 2 + c; ww = ww < 0 ? -ww : (ww > W_ - 1 ? 2 * (W_ - 1) - ww : ww);
        xin[s * XP + ci] = f2bs(xb[(size_t)ci * HW + hh * W_ + ww]);
    }
    __syncthreads();

    // ---- per-spatial sum of squares over cin
    for (int s = tid; s < NS; s += 256) {
        const bf16x8* p = (const bf16x8*)&xin[s * XP];
        float a = 0.f;
        #pragma unroll
        for (int c8 = 0; c8 < 8; ++c8) {
            bf16x8 v = p[c8];
            #pragma unroll
            for (int j = 0; j < 8; ++j) { float f = bs2f(v[j]); a += f * f; }
        }
        s2win[s] = a;
    }
    __syncthreads();

    // ---- xsq per output pixel (8 x 32): 5x5 window sum of s2win
    {
        int hr = tid >> 5, cl = tid & 31;
        float a = 0.f;
        #pragma unroll
        for (int kh = 0; kh < 5; ++kh)
            #pragma unroll
            for (int kw = 0; kw < 5; ++kw)
                a += s2win[(hr + kh) * NC + cl + kw];
        xsq[tid] = a;
    }

    f32x16 acc00, acc01, acc10, acc11;
    #pragma unroll
    for (int i = 0; i < 16; ++i) { acc00[i] = 0.f; acc01[i] = 0.f; acc10[i] = 0.f; acc11[i] = 0.f; }

    // ---- K loop: 25 taps x 64 cin, NO barriers
    const short* wb = wnb2 + (size_t)lane * 8;   // per-lane fragment base
    #pragma unroll 5
    for (int kk = 0; kk < KK; ++kk) {
        const int kh = kk / 5, kw = kk % 5;
        const int sp0 = (2 * wv + kh) * NC + n + kw;
        #pragma unroll
        for (int ks = 0; ks < 4; ++ks) {
            const int ko = ks * 16 + q * 8;
            bf16x8 a0 = *(const bf16x8*)&xin[sp0 * XP + ko];
            bf16x8 a1 = *(const bf16x8*)&xin[(sp0 + NC) * XP + ko];
            bf16x8 b0 = *(const bf16x8*)&wb[(size_t)((kk * 4 + ks) * 2 + 0) * 512];
            bf16x8 b1 = *(const bf16x8*)&wb[(size_t)((kk * 4 + ks) * 2 + 1) * 512];
            acc00 = __builtin_amdgcn_mfma_f32_32x32x16_bf16(a0, b0, acc00, 0, 0, 0);
            acc01 = __builtin_amdgcn_mfma_f32_32x32x16_bf16(a0, b1, acc01, 0, 0, 0);
            acc10 = __builtin_amdgcn_mfma_f32_32x32x16_bf16(a1, b0, acc10, 0, 0, 0);
            acc11 = __builtin_amdgcn_mfma_f32_32x32x16_bf16(a1, b1, acc11, 0, 0, 0);
        }
    }
    __syncthreads();                       // xin dead; reuse as trans

    // ---- epilogue: y = acc * rsqrt(xsq); transpose via LDS; coalesced store
    short* trans = xin;
    const int hrA = 2 * wv, hrB = 2 * wv + 1;
    #pragma unroll
    for (int g4 = 0; g4 < 4; ++g4) {
        int wc0 = 8 * g4 + 4 * q;
        s16x4 v00, v01, v10, v11;
        #pragma unroll
        for (int j = 0; j < 4; ++j) {
            float ia = rsqrtf(xsq[hrA * 32 + wc0 + j] + 1e-8f);
            float ib = rsqrtf(xsq[hrB * 32 + wc0 + j] + 1e-8f);
            v00[j] = f2bs(acc00[4 * g4 + j] * ia);
            v01[j] = f2bs(acc01[4 * g4 + j] * ia);
            v10[j] = f2bs(acc10[4 * g4 + j] * ib);
            v11[j] = f2bs(acc11[4 * g4 + j] * ib);
        }
        *(s16x4*)&trans[n * TP        + hrA * 32 + wc0] = v00;
        *(s16x4*)&trans[(32 + n) * TP + hrA * 32 + wc0] = v01;
        *(s16x4*)&trans[n * TP        + hrB * 32 + wc0] = v10;
        *(s16x4*)&trans[(32 + n) * TP + hrB * 32 + wc0] = v11;
    }
    __syncthreads();

    #pragma unroll
    for (int u = tid; u < 512; u += 256) { // (oc, hr): 32 bf16 = 64 B runs
        int oc = u >> 3, hr = u & 7;
        const short* src = &trans[oc * TP + hr * 32];
        __hip_bfloat16* dst = t + ((size_t)(b * COUT + oc) * H_ + h0 + hr) * W_ + w0;
        float4 a0 = *(const float4*)(src);
        float4 a1 = *(const float4*)(src + 8);
        float4 a2 = *(const float4*)(src + 16);
        float4 a3 = *(const float4*)(src + 24);
        *(float4*)(dst)      = a0;
        *(float4*)(dst + 8)  = a1;
        *(float4*)(dst + 16) = a2;
        *(float4*)(dst + 24) = a3;
    }
}

// ---------------- Kernel 2: depthwise 5x5 DoG, zero pad, fp32 out ------------
__global__ __launch_bounds__(256) void k_dog(const __hip_bfloat16* __restrict__ t,
                                             float* __restrict__ out) {
    __shared__ float tile[36 * 136];
    const int bo  = blockIdx.y;
    const int h0  = blockIdx.x * 32;
    const int tid = threadIdx.x;

    float sm[25];
    {
        const float se2 = 2.f * 1.2f * 1.2f;
        const float si2 = 2.f * 1.4f * 1.4f;
        const float twopi = 6.28318530717958647692f;
        const float ae = 1.f / (twopi * 1.2f * 1.2f);
        const float ai = 1.f / (twopi * 1.4f * 1.4f);
        const float c0 = ae - ai;
        #pragma unroll
        for (int kk = 0; kk < 25; ++kk) {
            int dx = kk / 5 - 2, dy = kk % 5 - 2;
            float r2 = (float)(dx * dx + dy * dy);
            sm[kk] = (ae * expf(-r2 / se2) - ai * expf(-r2 / si2)) / c0;
        }
    }

    const __hip_bfloat16* tc = t + (size_t)bo * HW;
    for (int idx = tid; idx < 36 * 132; idx += 256) {
        int rr = idx / 132, cc = idx % 132;
        int hh = h0 - 2 + rr, ww = cc - 2;
        float v = 0.f;
        if (hh >= 0 && hh < H_ && ww >= 0 && ww < W_) v = __bfloat162float(tc[hh * W_ + ww]);
        tile[rr * 136 + cc] = v;
    }
    __syncthreads();

    const int cq = tid & 31;
    const int r0 = tid >> 5;
    #pragma unroll
    for (int rr = 0; rr < 4; ++rr) {
        int r = r0 + 8 * rr;
        float s0 = 0.f, s1 = 0.f, s2 = 0.f, s3 = 0.f;
        #pragma unroll
        for (int kh = 0; kh < 5; ++kh) {
            const float* row = &tile[(r + kh) * 136 + cq * 4];
            f32x4 v0 = *(const f32x4*)(row);
            f32x4 v1 = *(const f32x4*)(row + 4);
            float vv[8] = { v0[0], v0[1], v0[2], v0[3], v1[0], v1[1], v1[2], v1[3] };
            #pragma unroll
            for (int kw = 0; kw < 5; ++kw) {
                float cf = sm[kh * 5 + kw];
                s0 += cf * vv[kw];
                s1 += cf * vv[kw + 1];
                s2 += cf * vv[kw + 2];
                s3 += cf * vv[kw + 3];
            }
        }
        float4 o4 = make_float4(s0, s1, s2, s3);
        *(float4*)&out[((size_t)bo * H_ + h0 + r) * W_ + cq * 4] = o4;
    }
}

// -----------------------------------------------------------------------------
extern "C" void kernel_launch(void* const* d_in, const int* in_sizes, int n_in,
                              void* d_out, int out_size, void* d_ws, size_t ws_size,
                              hipStream_t stream) {
    const float* x = (const float*)d_in[0];
    const float* w = (const float*)d_in[1];

    __hip_bfloat16* t = (__hip_bfloat16*)d_ws;    // 32 MiB intermediate

    // Fragment-ordered normalized bf16 weights in the TAIL of d_out (64 MiB):
    // k_wprep writes, k_conv reads, k_dog fully overwrites. 204800 B.
    short* wnb2 = (short*)((char*)d_out + (size_t)67108864 - 204800);

    k_wprep<<<KK, 256, 0, stream>>>(w, wnb2);

    dim3 g2(W_ / 32, H_ / 8, B_);    // 4 x 16 x 16 = 1024 blocks
    k_conv<<<g2, 256, 0, stream>>>(x, wnb2, t);

    dim3 g3(H_ / 32, B_ * COUT);     // 4 x 1024 blocks
    k_dog<<<g3, 256, 0, stream>>>(t, (float*)d_out);
}